// Round 6
// baseline (311.819 us; speedup 1.0000x reference)
//
#include <hip/hip_runtime.h>

#define S_LEN 2048
#define DH 64

typedef float f32x4 __attribute__((ext_vector_type(4)));
typedef __bf16 bf16x8 __attribute__((ext_vector_type(8)));

#define PTS 72   // P row stride (bf16 elems) for 64 keys + pad
#define MFMA16(A, B, C) __builtin_amdgcn_mfma_f32_16x16x32_bf16(A, B, C, 0, 0, 0)

__device__ __forceinline__ unsigned short f2bf(float f) {
    unsigned u = __builtin_bit_cast(unsigned, f);
    u += 0x7fffu + ((u >> 16) & 1u);
    return (unsigned short)(u >> 16);
}

__device__ __forceinline__ uint4 pack8(const float* s) {
    unsigned short h[8];
#pragma unroll
    for (int i = 0; i < 8; ++i) h[i] = f2bf(s[i]);
    return *(const uint4*)h;
}

// truncating pack: low short = a_hi16, high short = b_hi16 (1 VALU op)
__device__ __forceinline__ unsigned pack_tr(float a, float b) {
    return __builtin_amdgcn_perm(__builtin_bit_cast(unsigned, b),
                                 __builtin_bit_cast(unsigned, a), 0x07060302u);
}

__device__ __forceinline__ bf16x8 ld128(const unsigned short* p) {
    return __builtin_bit_cast(bf16x8, *(const uint4*)p);
}

__device__ __forceinline__ bf16x8 ones8() {
    uint4 ou; ou.x = 0x3F803F80u; ou.y = ou.x; ou.z = ou.x; ou.w = ou.x;
    return __builtin_bit_cast(bf16x8, ou);
}

// ---------------- fused pre-pass: K and V -> swizzled bf16 tile images -----
// K image(head,tile32): 32 rows x 64 d; (r, b*8+e) = K[r][(b^(r&7))*8+e]
// V image(head,tile32): 64 d x 32 keys; (d, kb*8+e) = V^T[d][(kb^((d>>1)&3))*8+e]
__global__ __launch_bounds__(256) void prep_kv(const float* __restrict__ k,
                                               const float* __restrict__ v,
                                               uint4* __restrict__ kimg,
                                               uint4* __restrict__ vimg) {
    __shared__ unsigned short tr[64 * 40];
    const int bid = blockIdx.x;
    const int t = threadIdx.x;
    if (bid < 4096) {
        const int r = t >> 3, b = t & 7;
        const int srcblk = b ^ (r & 7);
        const float* src = k + ((size_t)bid * 32 + r) * 64 + srcblk * 8;
        float buf[8];
        *(float4*)&buf[0] = *(const float4*)src;
        *(float4*)&buf[4] = *(const float4*)(src + 4);
        kimg[(size_t)bid * 256 + t] = pack8(buf);
    } else {
        const int vb = bid - 4096;
        const int r = t >> 3, cb = t & 7;
        const float* src = v + ((size_t)vb * 32 + r) * 64 + cb * 8;
        float buf[8];
        *(float4*)&buf[0] = *(const float4*)src;
        *(float4*)&buf[4] = *(const float4*)(src + 4);
#pragma unroll
        for (int i = 0; i < 8; ++i)
            tr[(cb * 8 + i) * 40 + r] = f2bf(buf[i]);
        __syncthreads();
        const int d = t >> 2, kb = t & 3;
        const int skb = kb ^ ((d >> 1) & 3);
        vimg[(size_t)vb * 256 + t] = *(const uint4*)&tr[d * 40 + skb * 8];
    }
}

// ---- paired body: two unmasked 16-row subtiles sharing K/V fragments ------
__device__ __forceinline__ void body_pair(
    const unsigned short* __restrict__ kt, const unsigned short* __restrict__ vt,
    unsigned short* __restrict__ pw0, unsigned short* __restrict__ pw1,
    const bf16x8* qf, f32x4 acc[2][4], f32x4* accl, int quad, int c)
{
    const int sw = c & 7;
    const bf16x8 ones = ones8();
#pragma unroll
    for (int mt = 0; mt < 4; ++mt) {
        const unsigned short* kr = kt + (mt * 16 + c) * 64;
        bf16x8 ka0 = ld128(kr + ((quad ^ sw) << 3));
        bf16x8 ka1 = ld128(kr + (((quad | 4) ^ sw) << 3));
        f32x4 s0 = (f32x4){0.f, 0.f, 0.f, 0.f};
        f32x4 s1 = (f32x4){0.f, 0.f, 0.f, 0.f};
        s0 = MFMA16(ka0, qf[0], s0);  s0 = MFMA16(ka1, qf[1], s0);
        s1 = MFMA16(ka0, qf[2], s1);  s1 = MFMA16(ka1, qf[3], s1);
#pragma unroll
        for (int s = 0; s < 2; ++s) {
            const f32x4 st = s ? s1 : s0;
            float p0 = exp2f(st[0]), p1 = exp2f(st[1]);
            float p2 = exp2f(st[2]), p3 = exp2f(st[3]);
            unsigned* pb = (unsigned*)(s ? pw1 : pw0) + c * (PTS / 2) + mt * 8 + quad * 2;
            *(uint2*)pb = make_uint2(pack_tr(p0, p1), pack_tr(p2, p3));
        }
    }
    bf16x8 pf00 = ld128(pw0 + c * PTS + quad * 8);
    bf16x8 pf10 = ld128(pw1 + c * PTS + quad * 8);
    bf16x8 pf01 = ld128(pw0 + c * PTS + 32 + quad * 8);
    bf16x8 pf11 = ld128(pw1 + c * PTS + 32 + quad * 8);
    accl[0] = MFMA16(pf00, ones, accl[0]);  accl[0] = MFMA16(pf01, ones, accl[0]);
    accl[1] = MFMA16(pf10, ones, accl[1]);  accl[1] = MFMA16(pf11, ones, accl[1]);
    const int vsw = (c >> 1) & 3;
#pragma unroll
    for (int dc = 0; dc < 4; ++dc) {
        const unsigned short* vr = vt + (dc * 16 + c) * 32 + ((quad ^ vsw) << 3);
        bf16x8 vf0 = ld128(vr);
        bf16x8 vf1 = ld128(vr + 2048);
        acc[0][dc] = MFMA16(pf00, vf0, acc[0][dc]);
        acc[0][dc] = MFMA16(pf01, vf1, acc[0][dc]);
        acc[1][dc] = MFMA16(pf10, vf0, acc[1][dc]);
        acc[1][dc] = MFMA16(pf11, vf1, acc[1][dc]);
    }
}

// ---- single-subtile body. MODE=-1: unmasked. MODE=0..3: diagonal tile -----
// (live 16-key chunks mt=0..MODE, chunk MODE masked, dead chunks zero-filled)
template <int MODE>
__device__ __forceinline__ void body_one(
    const unsigned short* __restrict__ kt, const unsigned short* __restrict__ vt,
    unsigned short* __restrict__ pw,
    bf16x8 qfA, bf16x8 qfB, f32x4* acc4, f32x4& accl,
    int jt, int qbase, int quad, int c)
{
    const int sw = c & 7;
    const bf16x8 ones = ones8();
    constexpr int MTN = (MODE < 0) ? 4 : (MODE + 1);
#pragma unroll
    for (int mt = 0; mt < MTN; ++mt) {
        const unsigned short* kr = kt + (mt * 16 + c) * 64;
        bf16x8 ka0 = ld128(kr + ((quad ^ sw) << 3));
        bf16x8 ka1 = ld128(kr + (((quad | 4) ^ sw) << 3));
        f32x4 s0 = (f32x4){0.f, 0.f, 0.f, 0.f};
        s0 = MFMA16(ka0, qfA, s0);  s0 = MFMA16(ka1, qfB, s0);
        float p[4];
        const int ig = qbase + c;
#pragma unroll
        for (int r = 0; r < 4; ++r) {
            float e = exp2f(s0[r]);
            if (MODE >= 0 && mt == MODE) {
                const int jg = jt * 64 + mt * 16 + quad * 4 + r;
                e = (jg > ig) ? 0.f : e;
            }
            p[r] = e;
        }
        unsigned* pb = (unsigned*)pw + c * (PTS / 2) + mt * 8 + quad * 2;
        *(uint2*)pb = make_uint2(pack_tr(p[0], p[1]), pack_tr(p[2], p[3]));
    }
    if (MODE >= 0) {
#pragma unroll
        for (int mt = MODE + 1; mt < 4; ++mt) {
            unsigned* pb = (unsigned*)pw + c * (PTS / 2) + mt * 8 + quad * 2;
            *(uint2*)pb = make_uint2(0u, 0u);
        }
    }
    constexpr bool CH1 = (MODE < 0) || (MODE >= 2);  // upper 32-key chunk live?
    bf16x8 pf0 = ld128(pw + c * PTS + quad * 8);
    accl = MFMA16(pf0, ones, accl);
    bf16x8 pf1 = pf0;
    if (CH1) {
        pf1 = ld128(pw + c * PTS + 32 + quad * 8);
        accl = MFMA16(pf1, ones, accl);
    }
    const int vsw = (c >> 1) & 3;
#pragma unroll
    for (int dc = 0; dc < 4; ++dc) {
        const unsigned short* vr = vt + (dc * 16 + c) * 32 + ((quad ^ vsw) << 3);
        acc4[dc] = MFMA16(pf0, ld128(vr), acc4[dc]);
        if (CH1) acc4[dc] = MFMA16(pf1, ld128(vr + 2048), acc4[dc]);
    }
}

// ---------------- main kernel: causal pair-balanced, 64-key tiles ----------
// Wave owns subtile pair (p, 127-p): exactly 33-34 bodies per wave, uniform.
__global__ __launch_bounds__(256, 4) void fa_kernel(
    const float* __restrict__ q,
    const uint4* __restrict__ kimg,
    const uint4* __restrict__ vimg,
    float* __restrict__ out)
{
    __shared__ unsigned short kt[64 * 64];        // 8 KB
    __shared__ unsigned short vt[2 * 64 * 32];    // 8 KB
    __shared__ unsigned short pt[4][2][16 * PTS]; // 18 KB

    const int tid  = threadIdx.x;
    const int lane = tid & 63;
    const int wave = tid >> 6;
    const int quad = lane >> 4;
    const int c    = lane & 15;

    const int bid = blockIdx.x;
    const int bh  = bid & 63;
    const int pg  = bid >> 6;                 // 0..15 (pg 0 = longest, launches first)

    const int p       = pg * 4 + wave;        // lo subtile 0..63
    const int hi      = 127 - p;              // hi subtile
    const int lo_diag = p >> 2;               // 64-key diag tile indices
    const int hi_diag = hi >> 2;
    const int blk_last = (127 - pg * 4) >> 2; // wave-0's hi_diag = block max
    const int qbase_lo = p * 16;
    const int qbase_hi = hi * 16;
    const int S3lo = p & 3;
    const int S3hi = 3 - S3lo;

    const size_t head_off = (size_t)bh * S_LEN * DH;

    // Q fragments: qf[0,1] = lo subtile, qf[2,3] = hi subtile (log2-domain)
    const float SCALE = 0.125f * 1.4426950408889634f;
    bf16x8 qf[4];
#pragma unroll
    for (int s = 0; s < 2; ++s) {
        const int qb = s ? qbase_hi : qbase_lo;
        const float* qrow = q + head_off + (size_t)(qb + c) * DH;
        float t0[8], t1[8];
#pragma unroll
        for (int i = 0; i < 8; ++i) t0[i] = qrow[quad * 8 + i] * SCALE;
#pragma unroll
        for (int i = 0; i < 8; ++i) t1[i] = qrow[32 + quad * 8 + i] * SCALE;
        qf[s * 2 + 0] = __builtin_bit_cast(bf16x8, pack8(t0));
        qf[s * 2 + 1] = __builtin_bit_cast(bf16x8, pack8(t1));
    }

    f32x4 acc[2][4];
#pragma unroll
    for (int s = 0; s < 2; ++s)
#pragma unroll
        for (int dc = 0; dc < 4; ++dc) acc[s][dc] = (f32x4){0.f, 0.f, 0.f, 0.f};
    f32x4 accl[2];
    accl[0] = (f32x4){0.f, 0.f, 0.f, 0.f};
    accl[1] = (f32x4){0.f, 0.f, 0.f, 0.f};

    const uint4* kin = kimg + (size_t)bh * 64 * 256 + tid;
    const uint4* vin = vimg + (size_t)bh * 64 * 256 + tid;
    unsigned short* pw0 = pt[wave][0];   // lo P scratch
    unsigned short* pw1 = pt[wave][1];   // hi P scratch

    uint4 kA = kin[0], kB = kin[256];
    uint4 vA = vin[0], vB = vin[256];
    for (int jt = 0; jt <= blk_last; ++jt) {
        __syncthreads();
        ((uint4*)kt)[tid] = kA;  ((uint4*)kt)[tid + 256] = kB;
        ((uint4*)vt)[tid] = vA;  ((uint4*)vt)[tid + 256] = vB;
        if (jt < blk_last) {
            kA = kin[(jt + 1) * 512];  kB = kin[(jt + 1) * 512 + 256];
            vA = vin[(jt + 1) * 512];  vB = vin[(jt + 1) * 512 + 256];
        }
        __syncthreads();

        if (jt < lo_diag) {
            body_pair(kt, vt, pw0, pw1, qf, acc, accl, quad, c);
        } else if (jt == lo_diag) {
            body_one<-1>(kt, vt, pw1, qf[2], qf[3], acc[1], accl[1], jt, qbase_hi, quad, c);
            switch (S3lo) {
                case 0: body_one<0>(kt, vt, pw0, qf[0], qf[1], acc[0], accl[0], jt, qbase_lo, quad, c); break;
                case 1: body_one<1>(kt, vt, pw0, qf[0], qf[1], acc[0], accl[0], jt, qbase_lo, quad, c); break;
                case 2: body_one<2>(kt, vt, pw0, qf[0], qf[1], acc[0], accl[0], jt, qbase_lo, quad, c); break;
                default: body_one<3>(kt, vt, pw0, qf[0], qf[1], acc[0], accl[0], jt, qbase_lo, quad, c); break;
            }
        } else if (jt < hi_diag) {
            body_one<-1>(kt, vt, pw1, qf[2], qf[3], acc[1], accl[1], jt, qbase_hi, quad, c);
        } else if (jt == hi_diag) {
            switch (S3hi) {
                case 0: body_one<0>(kt, vt, pw1, qf[2], qf[3], acc[1], accl[1], jt, qbase_hi, quad, c); break;
                case 1: body_one<1>(kt, vt, pw1, qf[2], qf[3], acc[1], accl[1], jt, qbase_hi, quad, c); break;
                case 2: body_one<2>(kt, vt, pw1, qf[2], qf[3], acc[1], accl[1], jt, qbase_hi, quad, c); break;
                default: body_one<3>(kt, vt, pw1, qf[2], qf[3], acc[1], accl[1], jt, qbase_hi, quad, c); break;
            }
        }
        // waves 1..3 idle for up to 1 trailing iter (blk_last - hi_diag <= 1)
    }

    // ---- epilogue: l in accl (row = quad*4+r), normalize, store fp32 ----
    float* ob = out + head_off;
#pragma unroll
    for (int s = 0; s < 2; ++s) {
        const int qb = s ? qbase_hi : qbase_lo;
        float linv[4];
#pragma unroll
        for (int r = 0; r < 4; ++r) linv[r] = 1.0f / accl[s][r];
#pragma unroll
        for (int dc = 0; dc < 4; ++dc)
#pragma unroll
            for (int r = 0; r < 4; ++r) {
                const size_t idx = (size_t)(qb + quad * 4 + r) * DH + dc * 16 + c;
                ob[idx] = acc[s][dc][r] * linv[r];
            }
    }
}

// ---------------- fallback (round-2 style, used if ws too small) ----------
#define KT_STRIDE 88
#define VT_STRIDE 36
__global__ __launch_bounds__(256) void fa_kernel_fb(
    const float* __restrict__ q, const float* __restrict__ k,
    const float* __restrict__ v, float* __restrict__ out)
{
    __shared__ unsigned short kts[32 * KT_STRIDE];
    __shared__ unsigned short vts[64 * VT_STRIDE];
    __shared__ unsigned short pts[4][16 * 40];
    const int tid = threadIdx.x, lane = tid & 63, wave = tid >> 6;
    const int quad = lane >> 4, c = lane & 15;
    const int bid = blockIdx.x, bh = bid & 63, qblk = 31 - (bid >> 6);
    const int qtile = qblk * 4 + wave, qbase = qtile * 16;
    const int my_diag = qtile >> 1, jt_last = (qblk * 4 + 3) >> 1;
    const size_t head_off = (size_t)bh * S_LEN * DH;
    const float* qrow = q + head_off + (size_t)(qbase + c) * DH;
    float qtmp[8];
#pragma unroll
    for (int i = 0; i < 8; ++i) qtmp[i] = qrow[quad * 8 + i];
    bf16x8 qf0 = __builtin_bit_cast(bf16x8, pack8(qtmp));
#pragma unroll
    for (int i = 0; i < 8; ++i) qtmp[i] = qrow[32 + quad * 8 + i];
    bf16x8 qf1 = __builtin_bit_cast(bf16x8, pack8(qtmp));
    f32x4 acc[4];
#pragma unroll
    for (int dc = 0; dc < 4; ++dc) acc[dc] = (f32x4){0.f, 0.f, 0.f, 0.f};
    float m_run = -1e30f, l_run = 0.f;
    const int ig = qbase + c;
    const int srow = tid >> 3, sdb = tid & 7;
    const int vcol = (((srow >> 3) ^ (sdb & 3)) << 3) | (srow & 7);
    const float LOG2E = 1.4426950408889634f;
    for (int jt = 0; jt <= jt_last; ++jt) {
        __syncthreads();
        {
            const size_t g = head_off + (size_t)(jt * 32 + srow) * DH + sdb * 8;
            float kbuf[8];
            *(float4*)&kbuf[0] = *(const float4*)(k + g);
            *(float4*)&kbuf[4] = *(const float4*)(k + g + 4);
            *(uint4*)&kts[srow * KT_STRIDE + sdb * 8] = pack8(kbuf);
            float vbuf[8];
            *(float4*)&vbuf[0] = *(const float4*)(v + g);
            *(float4*)&vbuf[4] = *(const float4*)(v + g + 4);
#pragma unroll
            for (int i = 0; i < 8; ++i)
                vts[(sdb * 8 + i) * VT_STRIDE + vcol] = f2bf(vbuf[i]);
        }
        __syncthreads();
        if (jt > my_diag) continue;
        f32x4 st[2];
#pragma unroll
        for (int mt = 0; mt < 2; ++mt) {
            const unsigned short* krow = &kts[(mt * 16 + c) * KT_STRIDE + quad * 8];
            bf16x8 ka0 = __builtin_bit_cast(bf16x8, *(const uint4*)krow);
            bf16x8 ka1 = __builtin_bit_cast(bf16x8, *(const uint4*)(krow + 32));
            f32x4 a = (f32x4){0.f, 0.f, 0.f, 0.f};
            a = MFMA16(ka0, qf0, a);
            a = MFMA16(ka1, qf1, a);
            st[mt] = a;
        }
        float tv[8];
#pragma unroll
        for (int mt = 0; mt < 2; ++mt)
#pragma unroll
            for (int r = 0; r < 4; ++r) {
                const int jg = jt * 32 + mt * 16 + quad * 4 + r;
                const float s = st[mt][r] * 0.125f;
                tv[mt * 4 + r] = (jg > ig) ? -1e30f : s;
            }
        float tm = tv[0];
#pragma unroll
        for (int i = 1; i < 8; ++i) tm = fmaxf(tm, tv[i]);
        tm = fmaxf(tm, __shfl_xor(tm, 16, 64));
        tm = fmaxf(tm, __shfl_xor(tm, 32, 64));
        const float m_new = fmaxf(m_run, tm);
        const float mb = m_new * LOG2E;
        float p[8], ps = 0.f;
#pragma unroll
        for (int i = 0; i < 8; ++i) { p[i] = exp2f(tv[i] * LOG2E - mb); ps += p[i]; }
        ps += __shfl_xor(ps, 16, 64);
        ps += __shfl_xor(ps, 32, 64);
        const float alpha = exp2f((m_run - m_new) * LOG2E);
        l_run = l_run * alpha + ps;
        m_run = m_new;
        unsigned short* pwf = pts[wave];
#pragma unroll
        for (int mt = 0; mt < 2; ++mt)
#pragma unroll
            for (int r = 0; r < 4; ++r)
                pwf[c * 40 + mt * 16 + quad * 4 + r] = f2bf(p[mt * 4 + r]);
        float ar[4];
#pragma unroll
        for (int r = 0; r < 4; ++r)
            ar[r] = __shfl(alpha, (quad << 4) + quad * 4 + r, 64);
#pragma unroll
        for (int dc = 0; dc < 4; ++dc)
#pragma unroll
            for (int r = 0; r < 4; ++r) acc[dc][r] *= ar[r];
        bf16x8 pf = __builtin_bit_cast(bf16x8, *(const uint4*)&pwf[c * 40 + quad * 8]);
#pragma unroll
        for (int dc = 0; dc < 4; ++dc) {
            const int vrow = dc * 16 + c;
            const int blk = quad ^ ((vrow >> 3) & 3);
            const unsigned short* vp = &vts[vrow * VT_STRIDE + blk * 8];
            uint2 a0 = *(const uint2*)vp;
            uint2 a1 = *(const uint2*)(vp + 4);
            uint4 u; u.x = a0.x; u.y = a0.y; u.z = a1.x; u.w = a1.y;
            bf16x8 vf = __builtin_bit_cast(bf16x8, u);
            acc[dc] = MFMA16(pf, vf, acc[dc]);
        }
    }
    float linv[4];
#pragma unroll
    for (int r = 0; r < 4; ++r) {
        const float lr = __shfl(l_run, (quad << 4) + quad * 4 + r, 64);
        linv[r] = 1.0f / lr;
    }
    float* ob = out + head_off;
#pragma unroll
    for (int dc = 0; dc < 4; ++dc)
#pragma unroll
        for (int r = 0; r < 4; ++r) {
            const size_t idx = (size_t)(qbase + quad * 4 + r) * DH + dc * 16 + c;
            ob[idx] = acc[dc][r] * linv[r];
        }
}

extern "C" void kernel_launch(void* const* d_in, const int* in_sizes, int n_in,
                              void* d_out, int out_size, void* d_ws, size_t ws_size,
                              hipStream_t stream) {
    const float* q = (const float*)d_in[0];
    const float* k = (const float*)d_in[1];
    const float* v = (const float*)d_in[2];
    float* o = (float*)d_out;
    const size_t need = (size_t)2 * 64 * 64 * 4096;  // K + V bf16 tile images
    if (ws_size >= need) {
        uint4* kimg = (uint4*)d_ws;
        uint4* vimg = kimg + (size_t)64 * 64 * 256;
        hipLaunchKernelGGL(prep_kv, dim3(8192), dim3(256), 0, stream, k, v, kimg, vimg);
        hipLaunchKernelGGL(fa_kernel, dim3(1024), dim3(256), 0, stream, q, kimg, vimg, o);
    } else {
        hipLaunchKernelGGL(fa_kernel_fb, dim3(2048), dim3(256), 0, stream, q, k, v, o);
    }
}

// Round 7
// 194.330 us; speedup vs baseline: 1.6046x; 1.6046x over previous
//
#include <hip/hip_runtime.h>

#define S_LEN 2048
#define DH 64

typedef float f32x4 __attribute__((ext_vector_type(4)));
typedef __bf16 bf16x8 __attribute__((ext_vector_type(8)));

#define PT_STRIDE 36   // P row stride in bf16 elems (u32 stride 18: conflict-free)
#define MFMA16(A, B, C) __builtin_amdgcn_mfma_f32_16x16x32_bf16(A, B, C, 0, 0, 0)

__device__ __forceinline__ unsigned short f2bf(float f) {
    unsigned u = __builtin_bit_cast(unsigned, f);
    u += 0x7fffu + ((u >> 16) & 1u);
    return (unsigned short)(u >> 16);
}

__device__ __forceinline__ uint4 pack8(const float* s) {
    unsigned short h[8];
#pragma unroll
    for (int i = 0; i < 8; ++i) h[i] = f2bf(s[i]);
    return *(const uint4*)h;
}

// truncating pack: low short = a_hi16, high short = b_hi16 (1 VALU op).
// Truncation bias cancels in O = (P V) / (P 1) since l uses the same P.
__device__ __forceinline__ unsigned pack_tr(float a, float b) {
    return __builtin_amdgcn_perm(__builtin_bit_cast(unsigned, b),
                                 __builtin_bit_cast(unsigned, a), 0x07060302u);
}

__device__ __forceinline__ bf16x8 ld128(const unsigned short* p) {
    return __builtin_bit_cast(bf16x8, *(const uint4*)p);
}

__device__ __forceinline__ bf16x8 ones8() {
    uint4 ou; ou.x = 0x3F803F80u; ou.y = ou.x; ou.z = ou.x; ou.w = ou.x;
    return __builtin_bit_cast(bf16x8, ou);
}

// ---------------- fused pre-pass: K and V -> swizzled bf16 tile images -----
// K image(head,tile32): 32 rows x 64 d; (r, b*8+e) = K[r][(b^(r&7))*8+e]
// V image(head,tile32): 64 d x 32 keys; (d, kb*8+e) = V^T[d][(kb^((d>>1)&3))*8+e]
__global__ __launch_bounds__(256) void prep_kv(const float* __restrict__ k,
                                               const float* __restrict__ v,
                                               uint4* __restrict__ kimg,
                                               uint4* __restrict__ vimg) {
    __shared__ unsigned short tr[64 * 40];
    const int bid = blockIdx.x;
    const int t = threadIdx.x;
    if (bid < 4096) {
        const int r = t >> 3, b = t & 7;
        const int srcblk = b ^ (r & 7);
        const float* src = k + ((size_t)bid * 32 + r) * 64 + srcblk * 8;
        float buf[8];
        *(float4*)&buf[0] = *(const float4*)src;
        *(float4*)&buf[4] = *(const float4*)(src + 4);
        kimg[(size_t)bid * 256 + t] = pack8(buf);
    } else {
        const int vb = bid - 4096;
        const int r = t >> 3, cb = t & 7;
        const float* src = v + ((size_t)vb * 32 + r) * 64 + cb * 8;
        float buf[8];
        *(float4*)&buf[0] = *(const float4*)src;
        *(float4*)&buf[4] = *(const float4*)(src + 4);
#pragma unroll
        for (int i = 0; i < 8; ++i)
            tr[(cb * 8 + i) * 40 + r] = f2bf(buf[i]);
        __syncthreads();
        const int d = t >> 2, kb = t & 3;
        const int skb = kb ^ ((d >> 1) & 3);
        vimg[(size_t)vb * 256 + t] = *(const uint4*)&tr[d * 40 + skb * 8];
    }
}

// ---------------- main flash-attention kernel (round-4 structure) ----------
template <bool MASKED>
__device__ __forceinline__ void tile_body(
    const unsigned short* __restrict__ kt, const unsigned short* __restrict__ vt,
    unsigned short* __restrict__ pw,
    bf16x8 qf0, bf16x8 qf1, f32x4* acc, f32x4& accl,
    int jt, int ig, int quad, int c)
{
    // ---- S^T = K . Q^T (Q pre-scaled by 0.125*log2e) ----
    f32x4 st[2];
    const int sw = c & 7;
#pragma unroll
    for (int mt = 0; mt < 2; ++mt) {
        const unsigned short* kr = kt + (mt * 16 + c) * 64;
        bf16x8 ka0 = ld128(kr + ((quad ^ sw) << 3));
        bf16x8 ka1 = ld128(kr + (((quad | 4) ^ sw) << 3));
        f32x4 a = (f32x4){0.f, 0.f, 0.f, 0.f};
        a = MFMA16(ka0, qf0, a);
        a = MFMA16(ka1, qf1, a);
        st[mt] = a;
    }

    // ---- unnormalized softmax: p = exp2(s) via raw v_exp_f32 ----
    float p[8];
#pragma unroll
    for (int mt = 0; mt < 2; ++mt)
#pragma unroll
        for (int r = 0; r < 4; ++r) {
            float e = __builtin_amdgcn_exp2f(st[mt][r]);
            if (MASKED) {
                const int jg = jt * 32 + mt * 16 + quad * 4 + r;
                e = (jg > ig) ? 0.f : e;
            }
            p[mt * 4 + r] = e;
        }

    // ---- P -> per-wave LDS (C-layout pairs), gather as A-layout ----
    unsigned* pb = (unsigned*)pw + c * (PT_STRIDE / 2);
#pragma unroll
    for (int mt = 0; mt < 2; ++mt) {
        uint2 w;
        w.x = pack_tr(p[mt * 4 + 0], p[mt * 4 + 1]);
        w.y = pack_tr(p[mt * 4 + 2], p[mt * 4 + 3]);
        *(uint2*)(pb + mt * 8 + quad * 2) = w;
    }

    const unsigned short* pr = pw + c * PT_STRIDE + quad * 8;
    uint2 lo = *(const uint2*)pr;
    uint2 hi = *(const uint2*)(pr + 4);
    uint4 pu; pu.x = lo.x; pu.y = lo.y; pu.z = hi.x; pu.w = hi.y;
    bf16x8 pf = __builtin_bit_cast(bf16x8, pu);

    // ---- l += P . 1 via MFMA (row = quad*4+r in accl) ----
    accl = MFMA16(pf, ones8(), accl);

    // ---- O += P . V ----
    const int vsw = (c >> 1) & 3;
#pragma unroll
    for (int dc = 0; dc < 4; ++dc) {
        const unsigned short* vp = vt + (dc * 16 + c) * 32 + ((quad ^ vsw) << 3);
        acc[dc] = MFMA16(pf, ld128(vp), acc[dc]);
    }
}

__global__ __launch_bounds__(256) void fa_kernel(
    const float* __restrict__ q,
    const uint4* __restrict__ kimg,
    const uint4* __restrict__ vimg,
    float* __restrict__ out)
{
    __shared__ unsigned short kt[32 * 64];
    __shared__ unsigned short vt[64 * 32];
    __shared__ unsigned short pt[4][16 * PT_STRIDE];

    const int tid  = threadIdx.x;
    const int lane = tid & 63;
    const int wave = tid >> 6;
    const int quad = lane >> 4;
    const int c    = lane & 15;

    const int bid  = blockIdx.x;
    const int bh   = bid & 63;
    const int qblk = 31 - (bid >> 6);          // longest blocks first

    const int qtile   = qblk * 4 + wave;
    const int qbase   = qtile * 16;
    const int diag    = qtile >> 1;
    const int jt_last = 2 * qblk + 1;

    const size_t head_off = (size_t)bh * S_LEN * DH;

    // Q fragments, pre-scaled into log2 domain
    const float SCALE = 0.125f * 1.4426950408889634f;
    const float* qrow = q + head_off + (size_t)(qbase + c) * DH;
    float qtmp[8];
#pragma unroll
    for (int i = 0; i < 8; ++i) qtmp[i] = qrow[quad * 8 + i] * SCALE;
    bf16x8 qf0 = __builtin_bit_cast(bf16x8, pack8(qtmp));
#pragma unroll
    for (int i = 0; i < 8; ++i) qtmp[i] = qrow[32 + quad * 8 + i] * SCALE;
    bf16x8 qf1 = __builtin_bit_cast(bf16x8, pack8(qtmp));

    f32x4 acc[4];
#pragma unroll
    for (int dc = 0; dc < 4; ++dc) acc[dc] = (f32x4){0.f, 0.f, 0.f, 0.f};
    f32x4 accl = (f32x4){0.f, 0.f, 0.f, 0.f};
    const int ig = qbase + c;

    const uint4* kin = kimg + (size_t)bh * 64 * 256 + tid;
    const uint4* vin = vimg + (size_t)bh * 64 * 256 + tid;
    unsigned short* pw = pt[wave];

    uint4 kreg = kin[0];
    uint4 vreg = vin[0];
    for (int jt = 0; jt <= jt_last; ++jt) {
        __syncthreads();
        ((uint4*)kt)[tid] = kreg;
        ((uint4*)vt)[tid] = vreg;
        if (jt < jt_last) {
            kreg = kin[(jt + 1) * 256];
            vreg = vin[(jt + 1) * 256];
        }
        __syncthreads();

        if (jt < diag)
            tile_body<false>(kt, vt, pw, qf0, qf1, acc, accl, jt, ig, quad, c);
        else if (jt == diag)
            tile_body<true>(kt, vt, pw, qf0, qf1, acc, accl, jt, ig, quad, c);
    }

    // ---- epilogue: l lives in accl (row = quad*4+r), normalize, store ----
    float linv[4];
#pragma unroll
    for (int r = 0; r < 4; ++r) linv[r] = 1.0f / accl[r];

    float* ob = out + head_off;
#pragma unroll
    for (int dc = 0; dc < 4; ++dc)
#pragma unroll
        for (int r = 0; r < 4; ++r) {
            const size_t idx = (size_t)(qbase + quad * 4 + r) * DH + dc * 16 + c;
            ob[idx] = acc[dc][r] * linv[r];
        }
}

// ---------------- fallback (round-2 style, used if ws too small) ----------
#define KT_STRIDE 88
#define VT_STRIDE 36
__global__ __launch_bounds__(256) void fa_kernel_fb(
    const float* __restrict__ q, const float* __restrict__ k,
    const float* __restrict__ v, float* __restrict__ out)
{
    __shared__ unsigned short kts[32 * KT_STRIDE];
    __shared__ unsigned short vts[64 * VT_STRIDE];
    __shared__ unsigned short pts[4][16 * 40];
    const int tid = threadIdx.x, lane = tid & 63, wave = tid >> 6;
    const int quad = lane >> 4, c = lane & 15;
    const int bid = blockIdx.x, bh = bid & 63, qblk = 31 - (bid >> 6);
    const int qtile = qblk * 4 + wave, qbase = qtile * 16;
    const int my_diag = qtile >> 1, jt_last = (qblk * 4 + 3) >> 1;
    const size_t head_off = (size_t)bh * S_LEN * DH;
    const float* qrow = q + head_off + (size_t)(qbase + c) * DH;
    float qtmp[8];
#pragma unroll
    for (int i = 0; i < 8; ++i) qtmp[i] = qrow[quad * 8 + i];
    bf16x8 qf0 = __builtin_bit_cast(bf16x8, pack8(qtmp));
#pragma unroll
    for (int i = 0; i < 8; ++i) qtmp[i] = qrow[32 + quad * 8 + i];
    bf16x8 qf1 = __builtin_bit_cast(bf16x8, pack8(qtmp));
    f32x4 acc[4];
#pragma unroll
    for (int dc = 0; dc < 4; ++dc) acc[dc] = (f32x4){0.f, 0.f, 0.f, 0.f};
    float m_run = -1e30f, l_run = 0.f;
    const int ig = qbase + c;
    const int srow = tid >> 3, sdb = tid & 7;
    const int vcol = (((srow >> 3) ^ (sdb & 3)) << 3) | (srow & 7);
    const float LOG2E = 1.4426950408889634f;
    for (int jt = 0; jt <= jt_last; ++jt) {
        __syncthreads();
        {
            const size_t g = head_off + (size_t)(jt * 32 + srow) * DH + sdb * 8;
            float kbuf[8];
            *(float4*)&kbuf[0] = *(const float4*)(k + g);
            *(float4*)&kbuf[4] = *(const float4*)(k + g + 4);
            *(uint4*)&kts[srow * KT_STRIDE + sdb * 8] = pack8(kbuf);
            float vbuf[8];
            *(float4*)&vbuf[0] = *(const float4*)(v + g);
            *(float4*)&vbuf[4] = *(const float4*)(v + g + 4);
#pragma unroll
            for (int i = 0; i < 8; ++i)
                vts[(sdb * 8 + i) * VT_STRIDE + vcol] = f2bf(vbuf[i]);
        }
        __syncthreads();
        if (jt > my_diag) continue;
        f32x4 st[2];
#pragma unroll
        for (int mt = 0; mt < 2; ++mt) {
            const unsigned short* krow = &kts[(mt * 16 + c) * KT_STRIDE + quad * 8];
            bf16x8 ka0 = __builtin_bit_cast(bf16x8, *(const uint4*)krow);
            bf16x8 ka1 = __builtin_bit_cast(bf16x8, *(const uint4*)(krow + 32));
            f32x4 a = (f32x4){0.f, 0.f, 0.f, 0.f};
            a = MFMA16(ka0, qf0, a);
            a = MFMA16(ka1, qf1, a);
            st[mt] = a;
        }
        float tv[8];
#pragma unroll
        for (int mt = 0; mt < 2; ++mt)
#pragma unroll
            for (int r = 0; r < 4; ++r) {
                const int jg = jt * 32 + mt * 16 + quad * 4 + r;
                const float s = st[mt][r] * 0.125f;
                tv[mt * 4 + r] = (jg > ig) ? -1e30f : s;
            }
        float tm = tv[0];
#pragma unroll
        for (int i = 1; i < 8; ++i) tm = fmaxf(tm, tv[i]);
        tm = fmaxf(tm, __shfl_xor(tm, 16, 64));
        tm = fmaxf(tm, __shfl_xor(tm, 32, 64));
        const float m_new = fmaxf(m_run, tm);
        const float mb = m_new * LOG2E;
        float p[8], ps = 0.f;
#pragma unroll
        for (int i = 0; i < 8; ++i) {
            p[i] = __builtin_amdgcn_exp2f(tv[i] * LOG2E - mb);
            ps += p[i];
        }
        ps += __shfl_xor(ps, 16, 64);
        ps += __shfl_xor(ps, 32, 64);
        const float alpha = __builtin_amdgcn_exp2f((m_run - m_new) * LOG2E);
        l_run = l_run * alpha + ps;
        m_run = m_new;
        unsigned short* pwf = pts[wave];
#pragma unroll
        for (int mt = 0; mt < 2; ++mt)
#pragma unroll
            for (int r = 0; r < 4; ++r)
                pwf[c * 40 + mt * 16 + quad * 4 + r] = f2bf(p[mt * 4 + r]);
        float ar[4];
#pragma unroll
        for (int r = 0; r < 4; ++r)
            ar[r] = __shfl(alpha, (quad << 4) + quad * 4 + r, 64);
#pragma unroll
        for (int dc = 0; dc < 4; ++dc)
#pragma unroll
            for (int r = 0; r < 4; ++r) acc[dc][r] *= ar[r];
        bf16x8 pf = __builtin_bit_cast(bf16x8, *(const uint4*)&pwf[c * 40 + quad * 8]);
#pragma unroll
        for (int dc = 0; dc < 4; ++dc) {
            const int vrow = dc * 16 + c;
            const int blk = quad ^ ((vrow >> 3) & 3);
            const unsigned short* vp = &vts[vrow * VT_STRIDE + blk * 8];
            uint2 a0 = *(const uint2*)vp;
            uint2 a1 = *(const uint2*)(vp + 4);
            uint4 u; u.x = a0.x; u.y = a0.y; u.z = a1.x; u.w = a1.y;
            bf16x8 vf = __builtin_bit_cast(bf16x8, u);
            acc[dc] = MFMA16(pf, vf, acc[dc]);
        }
    }
    float linv[4];
#pragma unroll
    for (int r = 0; r < 4; ++r) {
        const float lr = __shfl(l_run, (quad << 4) + quad * 4 + r, 64);
        linv[r] = 1.0f / lr;
    }
    float* ob = out + head_off;
#pragma unroll
    for (int dc = 0; dc < 4; ++dc)
#pragma unroll
        for (int r = 0; r < 4; ++r) {
            const size_t idx = (size_t)(qbase + quad * 4 + r) * DH + dc * 16 + c;
            ob[idx] = acc[dc][r] * linv[r];
        }
}

extern "C" void kernel_launch(void* const* d_in, const int* in_sizes, int n_in,
                              void* d_out, int out_size, void* d_ws, size_t ws_size,
                              hipStream_t stream) {
    const float* q = (const float*)d_in[0];
    const float* k = (const float*)d_in[1];
    const float* v = (const float*)d_in[2];
    float* o = (float*)d_out;
    const size_t need = (size_t)2 * 64 * 64 * 4096;  // K + V bf16 tile images
    if (ws_size >= need) {
        uint4* kimg = (uint4*)d_ws;
        uint4* vimg = kimg + (size_t)64 * 64 * 256;
        hipLaunchKernelGGL(prep_kv, dim3(8192), dim3(256), 0, stream, k, v, kimg, vimg);
        hipLaunchKernelGGL(fa_kernel, dim3(2048), dim3(256), 0, stream, q, kimg, vimg, o);
    } else {
        hipLaunchKernelGGL(fa_kernel_fb, dim3(2048), dim3(256), 0, stream, q, k, v, o);
    }
}

// Round 8
// 185.221 us; speedup vs baseline: 1.6835x; 1.0492x over previous
//
#include <hip/hip_runtime.h>

#define S_LEN 2048
#define DH 64

typedef float f32x4 __attribute__((ext_vector_type(4)));
typedef __bf16 bf16x8 __attribute__((ext_vector_type(8)));

#define PTS 72   // P row stride (bf16 elems) for 64 keys + pad
#define MFMA16(A, B, C) __builtin_amdgcn_mfma_f32_16x16x32_bf16(A, B, C, 0, 0, 0)

__device__ __forceinline__ unsigned short f2bf(float f) {
    unsigned u = __builtin_bit_cast(unsigned, f);
    u += 0x7fffu + ((u >> 16) & 1u);
    return (unsigned short)(u >> 16);
}

__device__ __forceinline__ uint4 pack8(const float* s) {
    unsigned short h[8];
#pragma unroll
    for (int i = 0; i < 8; ++i) h[i] = f2bf(s[i]);
    return *(const uint4*)h;
}

// truncating pack (1 VALU op); bias cancels in O = (P V)/(P 1)
__device__ __forceinline__ unsigned pack_tr(float a, float b) {
    return __builtin_amdgcn_perm(__builtin_bit_cast(unsigned, b),
                                 __builtin_bit_cast(unsigned, a), 0x07060302u);
}

__device__ __forceinline__ bf16x8 ld128(const unsigned short* p) {
    return __builtin_bit_cast(bf16x8, *(const uint4*)p);
}

__device__ __forceinline__ bf16x8 ones8() {
    uint4 ou; ou.x = 0x3F803F80u; ou.y = ou.x; ou.z = ou.x; ou.w = ou.x;
    return __builtin_bit_cast(bf16x8, ou);
}

// ---------------- fused pre-pass: K and V -> swizzled bf16 tile images -----
__global__ __launch_bounds__(256) void prep_kv(const float* __restrict__ k,
                                               const float* __restrict__ v,
                                               uint4* __restrict__ kimg,
                                               uint4* __restrict__ vimg) {
    __shared__ unsigned short tr[64 * 40];
    const int bid = blockIdx.x;
    const int t = threadIdx.x;
    if (bid < 4096) {
        const int r = t >> 3, b = t & 7;
        const int srcblk = b ^ (r & 7);
        const float* src = k + ((size_t)bid * 32 + r) * 64 + srcblk * 8;
        float buf[8];
        *(float4*)&buf[0] = *(const float4*)src;
        *(float4*)&buf[4] = *(const float4*)(src + 4);
        kimg[(size_t)bid * 256 + t] = pack8(buf);
    } else {
        const int vb = bid - 4096;
        const int r = t >> 3, cb = t & 7;
        const float* src = v + ((size_t)vb * 32 + r) * 64 + cb * 8;
        float buf[8];
        *(float4*)&buf[0] = *(const float4*)src;
        *(float4*)&buf[4] = *(const float4*)(src + 4);
#pragma unroll
        for (int i = 0; i < 8; ++i)
            tr[(cb * 8 + i) * 40 + r] = f2bf(buf[i]);
        __syncthreads();
        const int d = t >> 2, kb = t & 3;
        const int skb = kb ^ ((d >> 1) & 3);
        vimg[(size_t)vb * 256 + t] = *(const uint4*)&tr[d * 40 + skb * 8];
    }
}

// ---------------- main kernel: 32 q-rows/wave, 64-key tiles ----------------
// DIAG: 0 = fully unmasked; 1 = even-wave diagonal (keys 32..63 dead, skip);
//       2 = odd-wave diagonal (mt 0,1 unmasked, mt 2,3 triangular)
template <int DIAG>
__device__ __forceinline__ void body64(
    const unsigned short* __restrict__ kt, const unsigned short* __restrict__ vt,
    unsigned short* __restrict__ pw0, unsigned short* __restrict__ pw1,
    const bf16x8* qf, f32x4 acc[2][4], f32x4* accl,
    int jt, int qbase, int quad, int c)
{
    const int sw = c & 7;
    const bf16x8 ones = ones8();
    const int MTN = (DIAG == 1) ? 2 : 4;

#pragma unroll
    for (int mt = 0; mt < MTN; ++mt) {
        const unsigned short* kr = kt + (mt * 16 + c) * 64;
        bf16x8 ka0 = ld128(kr + ((quad ^ sw) << 3));
        bf16x8 ka1 = ld128(kr + (((quad | 4) ^ sw) << 3));
        f32x4 s0 = (f32x4){0.f, 0.f, 0.f, 0.f};
        f32x4 s1 = (f32x4){0.f, 0.f, 0.f, 0.f};
        s0 = MFMA16(ka0, qf[0], s0);  s0 = MFMA16(ka1, qf[1], s0);
        s1 = MFMA16(ka0, qf[2], s1);  s1 = MFMA16(ka1, qf[3], s1);

        const bool MASKMT = (DIAG == 1) || (DIAG == 2 && mt >= 2);
#pragma unroll
        for (int s = 0; s < 2; ++s) {
            const f32x4 st = s ? s1 : s0;
            const int ig = qbase + s * 16 + c;
            float p[4];
#pragma unroll
            for (int r = 0; r < 4; ++r) {
                float e = __builtin_amdgcn_exp2f(st[r]);
                if (MASKMT) {
                    const int jg = jt * 64 + mt * 16 + quad * 4 + r;
                    e = (jg > ig) ? 0.f : e;
                }
                p[r] = e;
            }
            unsigned a = pack_tr(p[0], p[1]);
            unsigned b = pack_tr(p[2], p[3]);
            unsigned* pb = (unsigned*)(s ? pw1 : pw0) + c * (PTS / 2) + mt * 8 + quad * 2;
            *(uint2*)pb = make_uint2(a, b);
        }
    }

    // ---- P fragments (A-layout) + l via ones-MFMA ----
    bf16x8 pf00 = ld128(pw0 + c * PTS + quad * 8);
    bf16x8 pf10 = ld128(pw1 + c * PTS + quad * 8);
    accl[0] = MFMA16(pf00, ones, accl[0]);
    accl[1] = MFMA16(pf10, ones, accl[1]);
    bf16x8 pf01, pf11;
    if (DIAG != 1) {
        pf01 = ld128(pw0 + c * PTS + 32 + quad * 8);
        pf11 = ld128(pw1 + c * PTS + 32 + quad * 8);
        accl[0] = MFMA16(pf01, ones, accl[0]);
        accl[1] = MFMA16(pf11, ones, accl[1]);
    }

    // ---- O += P . V (V-frags shared across both q-subtiles) ----
    const int vsw = (c >> 1) & 3;
#pragma unroll
    for (int dc = 0; dc < 4; ++dc) {
        const unsigned short* vr = vt + (dc * 16 + c) * 32 + ((quad ^ vsw) << 3);
        bf16x8 vf0 = ld128(vr);
        acc[0][dc] = MFMA16(pf00, vf0, acc[0][dc]);
        acc[1][dc] = MFMA16(pf10, vf0, acc[1][dc]);
        if (DIAG != 1) {
            bf16x8 vf1 = ld128(vr + 2048);
            acc[0][dc] = MFMA16(pf01, vf1, acc[0][dc]);
            acc[1][dc] = MFMA16(pf11, vf1, acc[1][dc]);
        }
    }
}

__global__ __launch_bounds__(256, 4) void fa_kernel(
    const float* __restrict__ q,
    const uint4* __restrict__ kimg,
    const uint4* __restrict__ vimg,
    float* __restrict__ out)
{
    __shared__ unsigned short kt[64 * 64];        // 8 KB
    __shared__ unsigned short vt[2 * 64 * 32];    // 8 KB
    __shared__ unsigned short pt[4][2][16 * PTS]; // 18 KB

    const int tid  = threadIdx.x;
    const int lane = tid & 63;
    const int wave = tid >> 6;
    const int quad = lane >> 4;
    const int c    = lane & 15;

    const int bid = blockIdx.x;
    const int bh  = bid & 63;
    // Sum-balanced qblk ordering: CUs receive blocks {b, b+256, b+512, b+768}
    // under round-robin dispatch; these groups' qblks sum to 30 each
    // ({15,8,6,1},{14,9,5,2},{13,10,4,3},{12,11,7,0}) -> equal per-CU work.
    // Also (approx) longest-first as fallback if dispatch isn't round-robin.
    static const int qperm[16] = {15, 14, 13, 12, 8, 9, 10, 11,
                                  6, 5, 4, 3, 1, 2, 7, 0};
    const int qblk = qperm[bid >> 6];             // 0..15 (128 q-rows per block)

    const int wt      = qblk * 4 + wave;          // 32-row wave tile, 0..63
    const int qbase   = wt * 32;
    const int my_diag = wt >> 1;                  // 64-key diag tile index
    const int jt_last = 2 * qblk + 1;

    const size_t head_off = (size_t)bh * S_LEN * DH;

    // Q fragments for both 16-row subtiles, pre-scaled into log2 domain
    const float SCALE = 0.125f * 1.4426950408889634f;
    bf16x8 qf[4];
#pragma unroll
    for (int s = 0; s < 2; ++s) {
        const float* qrow = q + head_off + (size_t)(qbase + s * 16 + c) * DH;
        float t0[8], t1[8];
#pragma unroll
        for (int i = 0; i < 8; ++i) t0[i] = qrow[quad * 8 + i] * SCALE;
#pragma unroll
        for (int i = 0; i < 8; ++i) t1[i] = qrow[32 + quad * 8 + i] * SCALE;
        qf[s * 2 + 0] = __builtin_bit_cast(bf16x8, pack8(t0));
        qf[s * 2 + 1] = __builtin_bit_cast(bf16x8, pack8(t1));
    }

    f32x4 acc[2][4];
#pragma unroll
    for (int s = 0; s < 2; ++s)
#pragma unroll
        for (int dc = 0; dc < 4; ++dc) acc[s][dc] = (f32x4){0.f, 0.f, 0.f, 0.f};
    f32x4 accl[2];
    accl[0] = (f32x4){0.f, 0.f, 0.f, 0.f};
    accl[1] = (f32x4){0.f, 0.f, 0.f, 0.f};

    const uint4* kin = kimg + (size_t)bh * 64 * 256 + tid;
    const uint4* vin = vimg + (size_t)bh * 64 * 256 + tid;
    unsigned short* pw0 = pt[wave][0];
    unsigned short* pw1 = pt[wave][1];

    uint4 kA = kin[0], kB = kin[256];
    uint4 vA = vin[0], vB = vin[256];
    for (int jt = 0; jt <= jt_last; ++jt) {
        __syncthreads();
        ((uint4*)kt)[tid] = kA;  ((uint4*)kt)[tid + 256] = kB;
        ((uint4*)vt)[tid] = vA;  ((uint4*)vt)[tid + 256] = vB;
        if (jt < jt_last) {
            kA = kin[(jt + 1) * 512];  kB = kin[(jt + 1) * 512 + 256];
            vA = vin[(jt + 1) * 512];  vB = vin[(jt + 1) * 512 + 256];
        }
        __syncthreads();

        if (jt < my_diag) {
            body64<0>(kt, vt, pw0, pw1, qf, acc, accl, jt, qbase, quad, c);
        } else if (jt == my_diag) {
            if ((wt & 1) == 0)
                body64<1>(kt, vt, pw0, pw1, qf, acc, accl, jt, qbase, quad, c);
            else
                body64<2>(kt, vt, pw0, pw1, qf, acc, accl, jt, qbase, quad, c);
        }
    }

    // ---- epilogue: l lives in accl (row = quad*4+r), normalize, store ----
    float* ob = out + head_off;
#pragma unroll
    for (int s = 0; s < 2; ++s) {
        float linv[4];
#pragma unroll
        for (int r = 0; r < 4; ++r) linv[r] = 1.0f / accl[s][r];
#pragma unroll
        for (int dc = 0; dc < 4; ++dc)
#pragma unroll
            for (int r = 0; r < 4; ++r) {
                const size_t idx =
                    (size_t)(qbase + s * 16 + quad * 4 + r) * DH + dc * 16 + c;
                ob[idx] = acc[s][dc][r] * linv[r];
            }
    }
}

// ---------------- fallback (round-2 style, used if ws too small) ----------
#define KT_STRIDE 88
#define VT_STRIDE 36
__global__ __launch_bounds__(256) void fa_kernel_fb(
    const float* __restrict__ q, const float* __restrict__ k,
    const float* __restrict__ v, float* __restrict__ out)
{
    __shared__ unsigned short kts[32 * KT_STRIDE];
    __shared__ unsigned short vts[64 * VT_STRIDE];
    __shared__ unsigned short pts[4][16 * 40];
    const int tid = threadIdx.x, lane = tid & 63, wave = tid >> 6;
    const int quad = lane >> 4, c = lane & 15;
    const int bid = blockIdx.x, bh = bid & 63, qblk = 31 - (bid >> 6);
    const int qtile = qblk * 4 + wave, qbase = qtile * 16;
    const int my_diag = qtile >> 1, jt_last = (qblk * 4 + 3) >> 1;
    const size_t head_off = (size_t)bh * S_LEN * DH;
    const float* qrow = q + head_off + (size_t)(qbase + c) * DH;
    float qtmp[8];
#pragma unroll
    for (int i = 0; i < 8; ++i) qtmp[i] = qrow[quad * 8 + i];
    bf16x8 qf0 = __builtin_bit_cast(bf16x8, pack8(qtmp));
#pragma unroll
    for (int i = 0; i < 8; ++i) qtmp[i] = qrow[32 + quad * 8 + i];
    bf16x8 qf1 = __builtin_bit_cast(bf16x8, pack8(qtmp));
    f32x4 acc[4];
#pragma unroll
    for (int dc = 0; dc < 4; ++dc) acc[dc] = (f32x4){0.f, 0.f, 0.f, 0.f};
    float m_run = -1e30f, l_run = 0.f;
    const int ig = qbase + c;
    const int srow = tid >> 3, sdb = tid & 7;
    const int vcol = (((srow >> 3) ^ (sdb & 3)) << 3) | (srow & 7);
    const float LOG2E = 1.4426950408889634f;
    for (int jt = 0; jt <= jt_last; ++jt) {
        __syncthreads();
        {
            const size_t g = head_off + (size_t)(jt * 32 + srow) * DH + sdb * 8;
            float kbuf[8];
            *(float4*)&kbuf[0] = *(const float4*)(k + g);
            *(float4*)&kbuf[4] = *(const float4*)(k + g + 4);
            *(uint4*)&kts[srow * KT_STRIDE + sdb * 8] = pack8(kbuf);
            float vbuf[8];
            *(float4*)&vbuf[0] = *(const float4*)(v + g);
            *(float4*)&vbuf[4] = *(const float4*)(v + g + 4);
#pragma unroll
            for (int i = 0; i < 8; ++i)
                vts[(sdb * 8 + i) * VT_STRIDE + vcol] = f2bf(vbuf[i]);
        }
        __syncthreads();
        if (jt > my_diag) continue;
        f32x4 st[2];
#pragma unroll
        for (int mt = 0; mt < 2; ++mt) {
            const unsigned short* krow = &kts[(mt * 16 + c) * KT_STRIDE + quad * 8];
            bf16x8 ka0 = __builtin_bit_cast(bf16x8, *(const uint4*)krow);
            bf16x8 ka1 = __builtin_bit_cast(bf16x8, *(const uint4*)(krow + 32));
            f32x4 a = (f32x4){0.f, 0.f, 0.f, 0.f};
            a = MFMA16(ka0, qf0, a);
            a = MFMA16(ka1, qf1, a);
            st[mt] = a;
        }
        float tv[8];
#pragma unroll
        for (int mt = 0; mt < 2; ++mt)
#pragma unroll
            for (int r = 0; r < 4; ++r) {
                const int jg = jt * 32 + mt * 16 + quad * 4 + r;
                const float s = st[mt][r] * 0.125f;
                tv[mt * 4 + r] = (jg > ig) ? -1e30f : s;
            }
        float tm = tv[0];
#pragma unroll
        for (int i = 1; i < 8; ++i) tm = fmaxf(tm, tv[i]);
        tm = fmaxf(tm, __shfl_xor(tm, 16, 64));
        tm = fmaxf(tm, __shfl_xor(tm, 32, 64));
        const float m_new = fmaxf(m_run, tm);
        const float mb = m_new * LOG2E;
        float p[8], ps = 0.f;
#pragma unroll
        for (int i = 0; i < 8; ++i) {
            p[i] = __builtin_amdgcn_exp2f(tv[i] * LOG2E - mb);
            ps += p[i];
        }
        ps += __shfl_xor(ps, 16, 64);
        ps += __shfl_xor(ps, 32, 64);
        const float alpha = __builtin_amdgcn_exp2f((m_run - m_new) * LOG2E);
        l_run = l_run * alpha + ps;
        m_run = m_new;
        unsigned short* pwf = pts[wave];
#pragma unroll
        for (int mt = 0; mt < 2; ++mt)
#pragma unroll
            for (int r = 0; r < 4; ++r)
                pwf[c * 40 + mt * 16 + quad * 4 + r] = f2bf(p[mt * 4 + r]);
        float ar[4];
#pragma unroll
        for (int r = 0; r < 4; ++r)
            ar[r] = __shfl(alpha, (quad << 4) + quad * 4 + r, 64);
#pragma unroll
        for (int dc = 0; dc < 4; ++dc)
#pragma unroll
            for (int r = 0; r < 4; ++r) acc[dc][r] *= ar[r];
        bf16x8 pf = __builtin_bit_cast(bf16x8, *(const uint4*)&pwf[c * 40 + quad * 8]);
#pragma unroll
        for (int dc = 0; dc < 4; ++dc) {
            const int vrow = dc * 16 + c;
            const int blk = quad ^ ((vrow >> 3) & 3);
            const unsigned short* vp = &vts[vrow * VT_STRIDE + blk * 8];
            uint2 a0 = *(const uint2*)vp;
            uint2 a1 = *(const uint2*)(vp + 4);
            uint4 u; u.x = a0.x; u.y = a0.y; u.z = a1.x; u.w = a1.y;
            bf16x8 vf = __builtin_bit_cast(bf16x8, u);
            acc[dc] = MFMA16(pf, vf, acc[dc]);
        }
    }
    float linv[4];
#pragma unroll
    for (int r = 0; r < 4; ++r) {
        const float lr = __shfl(l_run, (quad << 4) + quad * 4 + r, 64);
        linv[r] = 1.0f / lr;
    }
    float* ob = out + head_off;
#pragma unroll
    for (int dc = 0; dc < 4; ++dc)
#pragma unroll
        for (int r = 0; r < 4; ++r) {
            const size_t idx = (size_t)(qbase + quad * 4 + r) * DH + dc * 16 + c;
            ob[idx] = acc[dc][r] * linv[r];
        }
}

extern "C" void kernel_launch(void* const* d_in, const int* in_sizes, int n_in,
                              void* d_out, int out_size, void* d_ws, size_t ws_size,
                              hipStream_t stream) {
    const float* q = (const float*)d_in[0];
    const float* k = (const float*)d_in[1];
    const float* v = (const float*)d_in[2];
    float* o = (float*)d_out;
    const size_t need = (size_t)2 * 64 * 64 * 4096;  // K + V bf16 tile images
    if (ws_size >= need) {
        uint4* kimg = (uint4*)d_ws;
        uint4* vimg = kimg + (size_t)64 * 64 * 256;
        hipLaunchKernelGGL(prep_kv, dim3(8192), dim3(256), 0, stream, k, v, kimg, vimg);
        hipLaunchKernelGGL(fa_kernel, dim3(1024), dim3(256), 0, stream, q, kimg, vimg, o);
    } else {
        hipLaunchKernelGGL(fa_kernel_fb, dim3(2048), dim3(256), 0, stream, q, k, v, o);
    }
}